// Round 7
// baseline (252.209 us; speedup 1.0000x reference)
//
#include <hip/hip_runtime.h>

#define NPIX   65536          // B*H*W
#define CCH    64
#define KCODE  1024
#define HW     4096
#define Q_ELEMS 4194304
#define LOSS0_OFF 4194304
#define LOSS1_OFF 4194305
#define IDX_OFF   4194306
#define PTILE  16             // pixels per block

// numpy pairwise_sum middle branch for n=64 on squares (bit-exact np.sum(x*x))
template <typename F>
__device__ __forceinline__ float np_pairwise64_sq(F v) {
    float r[8];
#pragma unroll
    for (int j = 0; j < 8; ++j) r[j] = __fmul_rn(v(j), v(j));
#pragma unroll
    for (int i = 8; i < 64; i += 8) {
#pragma unroll
        for (int j = 0; j < 8; ++j)
            r[j] = __fadd_rn(r[j], __fmul_rn(v(i + j), v(i + j)));
    }
    return __fadd_rn(
        __fadd_rn(__fadd_rn(r[0], r[1]), __fadd_rn(r[2], r[3])),
        __fadd_rn(__fadd_rn(r[4], r[5]), __fadd_rn(r[6], r[7])));
}

// prep v2: LDS-tile transpose, coalesced on both sides. 16 blocks x 256 thr.
// Block handles 64 codebook rows: load coalesced float4, transpose via LDS,
// store et c-row chunks (256B/wave); se from the same staged bits (same FP order).
__global__ void prep_kernel(const float* __restrict__ emb,
                            float* __restrict__ se, float* __restrict__ et,
                            float* __restrict__ out) {
    __shared__ float s_e[64][65];                      // +pad: conflict-free both axes
    const int t  = threadIdx.x;
    const int k0 = blockIdx.x << 6;
#pragma unroll
    for (int i = 0; i < 4; ++i) {
        const int q = (i << 8) + t;                    // float4 index 0..1023
        const float4 v = reinterpret_cast<const float4*>(emb + ((size_t)k0 << 6))[q];
        const int r = q >> 4, c4 = (q & 15) << 2;
        s_e[r][c4] = v.x; s_e[r][c4 + 1] = v.y; s_e[r][c4 + 2] = v.z; s_e[r][c4 + 3] = v.w;
    }
    __syncthreads();
    if (t < 64)
        se[k0 + t] = np_pairwise64_sq([&](int i) { return s_e[t][i]; });
#pragma unroll
    for (int i = 0; i < 16; ++i) {
        const int n = (i << 8) + t;                    // 0..4095
        const int c = n >> 6, kk = n & 63;
        et[((size_t)c << 10) + k0 + kk] = s_e[kk][c];  // wave: 256B contiguous
    }
    if ((blockIdx.x | t) == 0) { out[LOSS0_OFF] = 0.f; out[LOSS1_OFF] = 0.f; }
}

// main: block = 256 thr = 4 waves; 16 pixels per block; thread owns 4 codes.
// R7: z-tile in LDS (in-order DS -> counted lgkmcnt) + EXPLICIT depth-2
// software pipeline on the ev VMEM stream: rows c+2/c+3 issued at body top,
// consumed two bodies (~256 issue-cycles) later -> L2 latency (~200cy on the
// 256KB et working set) fully covered. No SMEM in the hot loop -> no
// lgkmcnt(0) drains. R6 lesson: depth-1 ev was the ~38% stall.
__launch_bounds__(256, 4)
__global__ void vq_kernel(const float* __restrict__ z,
                          const float* __restrict__ emb,
                          const float* __restrict__ se,
                          const float* __restrict__ et,
                          float* __restrict__ out) {
    __shared__ float s_z[CCH][PTILE];                  // 4KB z tile
    __shared__ float s_szz[PTILE];
    __shared__ unsigned long long s_cand[PTILE][129];  // halved via shfl pre-reduce; +pad
    __shared__ unsigned long long s_part[PTILE][16];
    __shared__ unsigned int s_k[PTILE];
    __shared__ float s_red[4];

    const int t    = threadIdx.x;
    const int lane = t & 63;
    const int wave = t >> 6;
    const int pg0  = blockIdx.x * PTILE;
    const int b    = pg0 >> 12;
    const int hw0  = pg0 & 4095;
    const float* zb = z + (size_t)b * CCH * HW + hw0;  // zb[c*HW + p], wave-uniform

    // stage z tile: 1024 floats, 4 per thread
#pragma unroll
    for (int i = 0; i < 4; ++i) {
        const int idx = (i << 8) + t;                  // 0..1023
        const int c = idx >> 4, p = idx & 15;
        s_z[c][p] = zb[(size_t)c * HW + p];
    }
    __syncthreads();

    // szz for the block's 16 pixels (np order) from the staged bits
    if (t < PTILE)
        s_szz[t] = np_pairwise64_sq([&](int i) { return s_z[i][t]; });
    __syncthreads();

    // ---- main accumulation: acc[j][p] = sum_c z[c][p] * E^T[c][4t+j] ----
    float acc[4][PTILE];
#pragma unroll
    for (int j = 0; j < 4; ++j)
#pragma unroll
        for (int p = 0; p < PTILE; ++p) acc[j][p] = 0.f;

    const float* ecol = et + (t << 2);                 // 4 consecutive codes
    float4 evp0 = *reinterpret_cast<const float4*>(ecol);          // row 0 in flight
    float4 evp1 = *reinterpret_cast<const float4*>(ecol + 1024);   // row 1 in flight

#pragma unroll 2
    for (int c = 0; c < CCH; ++c) {
        const int cn = (c + 2 <= CCH - 1) ? (c + 2) : (CCH - 1);   // clamp: tail loads row63 (unused)
        float4 evv;
        if ((c & 1) == 0) { evv = evp0; evp0 = *reinterpret_cast<const float4*>(ecol + (cn << 10)); }
        else              { evv = evp1; evp1 = *reinterpret_cast<const float4*>(ecol + (cn << 10)); }
        const float ev[4] = {evv.x, evv.y, evv.z, evv.w};
        float zrow[PTILE];                              // uniform ds_read_b128 x4 (broadcast)
#pragma unroll
        for (int q = 0; q < 4; ++q) {
            const float4 zq = *reinterpret_cast<const float4*>(&s_z[c][q << 2]);
            zrow[(q << 2) + 0] = zq.x;
            zrow[(q << 2) + 1] = zq.y;
            zrow[(q << 2) + 2] = zq.z;
            zrow[(q << 2) + 3] = zq.w;
        }
#pragma unroll
        for (int j = 0; j < 4; ++j)
#pragma unroll
            for (int p = 0; p < PTILE; ++p)
                acc[j][p] = __builtin_fmaf(zrow[p], ev[j], acc[j][p]);  // same chain as R3
    }

    // ---- finalize distances + per-thread best (tail; acc dies into best) ----
    float szzv[PTILE];
#pragma unroll
    for (int p = 0; p < PTILE; ++p) szzv[p] = s_szz[p];
    const float4 se4v = *reinterpret_cast<const float4*>(se + (t << 2));
    const float se4[4] = {se4v.x, se4v.y, se4v.z, se4v.w};

    unsigned long long best[PTILE];
#pragma unroll
    for (int p = 0; p < PTILE; ++p) best[p] = ~0ULL;

#pragma unroll
    for (int j = 0; j < 4; ++j) {
        const int kk = (t << 2) + j;
#pragma unroll
        for (int p = 0; p < PTILE; ++p) {
            // d = fl( fl(szz+se) - 2*dot )  (identical algebra to R3, absmax 0)
            float d = __fsub_rn(__fadd_rn(szzv[p], se4[j]), __fadd_rn(acc[j][p], acc[j][p]));
            unsigned long long cand =
                ((unsigned long long)__float_as_uint(d) << 32) | (unsigned)kk;
            best[p] = cand < best[p] ? cand : best[p];   // d>0 -> bit-order == value-order
        }
    }

    // stage 1.5: one butterfly step in registers (exact: u64 min over same set)
#pragma unroll
    for (int p = 0; p < PTILE; ++p) {
        unsigned long long o = __shfl_xor(best[p], 1, 64);
        best[p] = o < best[p] ? o : best[p];
    }
    if ((t & 1) == 0) {
#pragma unroll
        for (int p = 0; p < PTILE; ++p) s_cand[p][t >> 1] = best[p];
    }
    __syncthreads();

    {   // stage 2: 256 threads, each folds 8 of the 128 candidates of pixel t&15
        const int p = t & 15, g = t >> 4;
        unsigned long long m = s_cand[p][(g << 3)];
#pragma unroll
        for (int u = 1; u < 8; ++u) {
            unsigned long long v = s_cand[p][(g << 3) + u];
            m = v < m ? v : m;
        }
        s_part[p][g] = m;
    }
    __syncthreads();

    if (t < PTILE) {   // stage 3: final per-pixel min; packed low bits = first-index k
        unsigned long long m = s_part[t][0];
#pragma unroll
        for (int g = 1; g < 16; ++g) {
            unsigned long long v = s_part[t][g];
            m = v < m ? v : m;
        }
        const unsigned int k = (unsigned int)m;
        s_k[t] = k;
        out[IDX_OFF + pg0 + t] = (float)k;
    }
    __syncthreads();

    // epilogue: thread t -> pixel p=t&15, channels c = (t>>4) + 16u
    float lsum = 0.f;
    {
        const int p = t & 15, g = t >> 4;
        const int k = (int)s_k[p];
#pragma unroll
        for (int u = 0; u < 4; ++u) {
            const int c = g + (u << 4);
            float e    = emb[(size_t)k * CCH + c];
            float zc   = s_z[c][p];                      // staged bits == global bits
            float diff = __fsub_rn(e, zc);               // STE rounding as in R3
            out[((size_t)(b * CCH + c)) * HW + hw0 + p] = __fadd_rn(zc, diff);
            lsum = __builtin_fmaf(diff, diff, lsum);
        }
    }
#pragma unroll
    for (int off = 32; off > 0; off >>= 1) lsum += __shfl_down(lsum, off, 64);
    if (lane == 0) s_red[wave] = lsum;
    __syncthreads();
    if (t == 0) {
        float v = (s_red[0] + s_red[1] + s_red[2] + s_red[3]) * (1.0f / (float)Q_ELEMS);
        atomicAdd(out + LOSS0_OFF, v);   // codebook_loss
        atomicAdd(out + LOSS1_OFF, v);   // commitment_loss (same forward value)
    }
}

extern "C" void kernel_launch(void* const* d_in, const int* in_sizes, int n_in,
                              void* d_out, int out_size, void* d_ws, size_t ws_size,
                              hipStream_t stream) {
    const float* z   = (const float*)d_in[0];
    const float* emb = (const float*)d_in[1];
    float* out = (float*)d_out;
    float* se  = (float*)d_ws;                 // 1024 floats
    float* et  = se + KCODE;                   // 65536 floats (E^T)

    prep_kernel<<<dim3(16), dim3(256), 0, stream>>>(emb, se, et, out);
    vq_kernel<<<dim3(NPIX / PTILE), dim3(256), 0, stream>>>(z, emb, se, et, out);
}

// Round 8
// 189.955 us; speedup vs baseline: 1.3277x; 1.3277x over previous
//
#include <hip/hip_runtime.h>

#define NPIX   65536          // B*H*W
#define CCH    64
#define KCODE  1024
#define HW     4096
#define Q_ELEMS 4194304
#define LOSS0_OFF 4194304
#define LOSS1_OFF 4194305
#define IDX_OFF   4194306
#define PTILE  16             // pixels per block

// numpy pairwise_sum middle branch for n=64 on squares (bit-exact np.sum(x*x))
template <typename F>
__device__ __forceinline__ float np_pairwise64_sq(F v) {
    float r[8];
#pragma unroll
    for (int j = 0; j < 8; ++j) r[j] = __fmul_rn(v(j), v(j));
#pragma unroll
    for (int i = 8; i < 64; i += 8) {
#pragma unroll
        for (int j = 0; j < 8; ++j)
            r[j] = __fadd_rn(r[j], __fmul_rn(v(i + j), v(i + j)));
    }
    return __fadd_rn(
        __fadd_rn(__fadd_rn(r[0], r[1]), __fadd_rn(r[2], r[3])),
        __fadd_rn(__fadd_rn(r[4], r[5]), __fadd_rn(r[6], r[7])));
}

// prep v2 (kept from R7, verified absmax 0): LDS-tile transpose, coalesced on
// both sides. 16 blocks x 256 thr. Saves ~16us vs the scattered-read prep v1.
__global__ void prep_kernel(const float* __restrict__ emb,
                            float* __restrict__ se, float* __restrict__ et,
                            float* __restrict__ out) {
    __shared__ float s_e[64][65];                      // +pad: conflict-free both axes
    const int t  = threadIdx.x;
    const int k0 = blockIdx.x << 6;
#pragma unroll
    for (int i = 0; i < 4; ++i) {
        const int q = (i << 8) + t;                    // float4 index 0..1023
        const float4 v = reinterpret_cast<const float4*>(emb + ((size_t)k0 << 6))[q];
        const int r = q >> 4, c4 = (q & 15) << 2;
        s_e[r][c4] = v.x; s_e[r][c4 + 1] = v.y; s_e[r][c4 + 2] = v.z; s_e[r][c4 + 3] = v.w;
    }
    __syncthreads();
    if (t < 64)
        se[k0 + t] = np_pairwise64_sq([&](int i) { return s_e[t][i]; });
#pragma unroll
    for (int i = 0; i < 16; ++i) {
        const int n = (i << 8) + t;                    // 0..4095
        const int c = n >> 6, kk = n & 63;
        et[((size_t)c << 10) + k0 + kk] = s_e[kk][c];  // wave: 256B contiguous
    }
    if ((blockIdx.x | t) == 0) { out[LOSS0_OFF] = 0.f; out[LOSS1_OFF] = 0.f; }
}

// main: vq reverted VERBATIM to the R3 structure (best measured: 130.6us,
// VALUBusy 62%, VGPR 52, zero spills). R5/R6/R7 lesson: every manual
// restructure of the c-loop (wide SMEM, LDS zrow, rotating-register ev
// pipeline) lost to the compiler's own unroll-4 schedule of this plain loop.
__launch_bounds__(256, 4)
__global__ void vq_kernel(const float* __restrict__ z,
                          const float* __restrict__ emb,
                          const float* __restrict__ se,
                          const float* __restrict__ et,
                          float* __restrict__ out) {
    __shared__ float s_szz[PTILE];
    __shared__ unsigned long long s_cand[PTILE][129];  // halved via shfl pre-reduce; +pad
    __shared__ unsigned long long s_part[PTILE][16];
    __shared__ unsigned int s_k[PTILE];
    __shared__ float s_red[4];

    const int t    = threadIdx.x;
    const int lane = t & 63;
    const int wave = t >> 6;
    const int pg0  = blockIdx.x * PTILE;
    const int b    = pg0 >> 12;
    const int hw0  = pg0 & 4095;
    const float* zb = z + (size_t)b * CCH * HW + hw0;  // zb[c*HW + p], wave-uniform

    // szz for the block's 16 pixels (np order), lanes 0..15 of wave 0
    if (t < PTILE)
        s_szz[t] = np_pairwise64_sq([&](int i) { return zb[(size_t)i * HW + t]; });
    __syncthreads();

    // ---- main accumulation: acc[j][p] = sum_c z[c][p] * E^T[c][4t+j] ----
    float acc[4][PTILE];
#pragma unroll
    for (int j = 0; j < 4; ++j)
#pragma unroll
        for (int p = 0; p < PTILE; ++p) acc[j][p] = 0.f;

    const float* ecol = et + (t << 2);                 // 4 consecutive codes
#pragma unroll 4
    for (int c = 0; c < CCH; ++c) {
        const float4 evv = *reinterpret_cast<const float4*>(ecol + (c << 10));
        const float ev[4] = {evv.x, evv.y, evv.z, evv.w};
        float zrow[PTILE];                              // uniform -> s_load_dwordx16
#pragma unroll
        for (int p = 0; p < PTILE; ++p) zrow[p] = zb[(size_t)c * HW + p];
#pragma unroll
        for (int j = 0; j < 4; ++j)
#pragma unroll
            for (int p = 0; p < PTILE; ++p)
                acc[j][p] = __builtin_fmaf(zrow[p], ev[j], acc[j][p]);  // same chain as R2
    }

    // ---- finalize distances + per-thread best (tail; acc dies into best) ----
    float szzv[PTILE];
#pragma unroll
    for (int p = 0; p < PTILE; ++p) szzv[p] = s_szz[p];
    const float4 se4v = *reinterpret_cast<const float4*>(se + (t << 2));
    const float se4[4] = {se4v.x, se4v.y, se4v.z, se4v.w};

    unsigned long long best[PTILE];
#pragma unroll
    for (int p = 0; p < PTILE; ++p) best[p] = ~0ULL;

#pragma unroll
    for (int j = 0; j < 4; ++j) {
        const int kk = (t << 2) + j;
#pragma unroll
        for (int p = 0; p < PTILE; ++p) {
            // d = fl( fl(szz+se) - 2*dot )  (identical algebra to R2, absmax 0)
            float d = __fsub_rn(__fadd_rn(szzv[p], se4[j]), __fadd_rn(acc[j][p], acc[j][p]));
            unsigned long long cand =
                ((unsigned long long)__float_as_uint(d) << 32) | (unsigned)kk;
            best[p] = cand < best[p] ? cand : best[p];   // d>0 -> bit-order == value-order
        }
    }

    // stage 1.5: one butterfly step in registers (exact: u64 min over same set)
#pragma unroll
    for (int p = 0; p < PTILE; ++p) {
        unsigned long long o = __shfl_xor(best[p], 1, 64);
        best[p] = o < best[p] ? o : best[p];
    }
    if ((t & 1) == 0) {
#pragma unroll
        for (int p = 0; p < PTILE; ++p) s_cand[p][t >> 1] = best[p];
    }
    __syncthreads();

    {   // stage 2: 256 threads, each folds 8 of the 128 candidates of pixel t&15
        const int p = t & 15, g = t >> 4;
        unsigned long long m = s_cand[p][(g << 3)];
#pragma unroll
        for (int u = 1; u < 8; ++u) {
            unsigned long long v = s_cand[p][(g << 3) + u];
            m = v < m ? v : m;
        }
        s_part[p][g] = m;
    }
    __syncthreads();

    if (t < PTILE) {   // stage 3: final per-pixel min; packed low bits = first-index k
        unsigned long long m = s_part[t][0];
#pragma unroll
        for (int g = 1; g < 16; ++g) {
            unsigned long long v = s_part[t][g];
            m = v < m ? v : m;
        }
        const unsigned int k = (unsigned int)m;
        s_k[t] = k;
        out[IDX_OFF + pg0 + t] = (float)k;
    }
    __syncthreads();

    // epilogue: thread t -> pixel p=t&15, channels c = (t>>4) + 16u
    float lsum = 0.f;
    {
        const int p = t & 15, g = t >> 4;
        const int k = (int)s_k[p];
#pragma unroll
        for (int u = 0; u < 4; ++u) {
            const int c = g + (u << 4);
            float e    = emb[(size_t)k * CCH + c];
            float zc   = zb[(size_t)c * HW + p];
            float diff = __fsub_rn(e, zc);               // STE rounding as in R2
            out[((size_t)(b * CCH + c)) * HW + hw0 + p] = __fadd_rn(zc, diff);
            lsum = __builtin_fmaf(diff, diff, lsum);
        }
    }
#pragma unroll
    for (int off = 32; off > 0; off >>= 1) lsum += __shfl_down(lsum, off, 64);
    if (lane == 0) s_red[wave] = lsum;
    __syncthreads();
    if (t == 0) {
        float v = (s_red[0] + s_red[1] + s_red[2] + s_red[3]) * (1.0f / (float)Q_ELEMS);
        atomicAdd(out + LOSS0_OFF, v);   // codebook_loss
        atomicAdd(out + LOSS1_OFF, v);   // commitment_loss (same forward value)
    }
}

extern "C" void kernel_launch(void* const* d_in, const int* in_sizes, int n_in,
                              void* d_out, int out_size, void* d_ws, size_t ws_size,
                              hipStream_t stream) {
    const float* z   = (const float*)d_in[0];
    const float* emb = (const float*)d_in[1];
    float* out = (float*)d_out;
    float* se  = (float*)d_ws;                 // 1024 floats
    float* et  = se + KCODE;                   // 65536 floats (E^T)

    prep_kernel<<<dim3(16), dim3(256), 0, stream>>>(emb, se, et, out);
    vq_kernel<<<dim3(NPIX / PTILE), dim3(256), 0, stream>>>(z, emb, se, et, out);
}